// Round 6
// baseline (1147.797 us; speedup 1.0000x reference)
//
#include <hip/hip_runtime.h>
#include <math.h>

typedef __attribute__((ext_vector_type(8))) short bf16x8;   // 8 bf16 in 4 VGPRs
typedef __attribute__((ext_vector_type(4))) float f32x4;

#define N_ROWS (16 * 16384)          // 262144 rows
#define D 64
#define K 512
#define BLOCK 256                    // 4 waves; each wave owns 64 rows
#define ROWS_PER_BLOCK 256
#define GRID (N_ROWS / ROWS_PER_BLOCK)   // 1024 blocks
#define MARGIN 1e-4f                 // ~10x the approx-vs-exact score error bound
#define FIXBLOCKS 256                // 1024 waves for the cleanup scan

// d_out layout (float element offsets), outputs concatenated in return order:
// vq_loss[1], quantized_st[N*D], perplexity[1], encodings[N*K], indices[N]
#define OFF_LOSS 0ULL
#define OFF_Q    1ULL
#define OFF_PERP (1ULL + (unsigned long long)N_ROWS * D)        // 16777217
#define OFF_ENC  (OFF_PERP + 1ULL)                               // 16777218
#define OFF_IDX  (OFF_ENC + (unsigned long long)N_ROWS * K)      // 150994946

// ws layout (u32 offsets). TOTAL ws use = 2112 bytes (R5 used 332 KB —
// suspected ws_size overflow; this round stays within the R1-R4-proven range).
#define WS_LOSS 0      // f32
#define WS_HIST 16     // u32[512]

__device__ __forceinline__ unsigned short f2bf(float f) {     // RNE fp32->bf16
    unsigned int u = __float_as_uint(f);
    return (unsigned short)((u + 0x7FFFu + ((u >> 16) & 1u)) >> 16);
}
__device__ __forceinline__ float bf2f(unsigned short h) {
    return __uint_as_float(((unsigned int)h) << 16);
}
__device__ __forceinline__ void cvt8(float4 a, float4 b, bf16x8* hi, bf16x8* lo) {
    float v[8] = {a.x, a.y, a.z, a.w, b.x, b.y, b.z, b.w};
    #pragma unroll
    for (int j = 0; j < 8; j++) {
        unsigned short h = f2bf(v[j]);
        (*hi)[j] = (short)h;
        (*lo)[j] = (short)f2bf(v[j] - bf2f(h));
    }
}

// ---- main: MFMA split-bf16 distances + argmin + all outputs ----
__global__ __launch_bounds__(BLOCK, 2) void vq_main(
    const float* __restrict__ x, const float* __restrict__ emb,
    float* __restrict__ out, unsigned int* __restrict__ ws)
{
    __shared__ float lds_se[K];                // 2 KB ||e||^2
    __shared__ unsigned int bk_lds[BLOCK];     // per-row winner (+flag bit31)
    __shared__ unsigned int lds_hist[K];

    const int tid = threadIdx.x, lane = tid & 63, wave = tid >> 6;
    const int m = lane & 15, g = lane >> 4;    // MFMA lane decomposition
    const int rowbase = blockIdx.x * ROWS_PER_BLOCK + wave * 64;
    const int wbase = wave * 64;

    lds_hist[tid] = 0; lds_hist[tid + BLOCK] = 0;

    // ||e||^2 table (single-chain order; used only in the margin-guarded score)
    for (int k = tid; k < K; k += BLOCK) {
        const float4* e4 = (const float4*)(emb + (size_t)k * D);
        float s = 0.f;
        #pragma unroll
        for (int i = 0; i < 16; i++) {
            float4 e = e4[i];
            s = fmaf(e.x, e.x, s); s = fmaf(e.y, e.y, s);
            s = fmaf(e.z, e.z, s); s = fmaf(e.w, e.w, s);
        }
        lds_se[k] = s;
    }

    // A-fragments: 64 rows as bf16 hi/lo. A[m=lane&15][k=g*8+j], per K=32 window
    bf16x8 Ah[4][2], Al[4][2];
    #pragma unroll
    for (int t = 0; t < 4; t++) {
        const float* xb = x + (size_t)(rowbase + t * 16 + m) * D + g * 8;
        cvt8(*(const float4*)(xb),      *(const float4*)(xb + 4),  &Ah[t][0], &Al[t][0]);
        cvt8(*(const float4*)(xb + 32), *(const float4*)(xb + 36), &Ah[t][1], &Al[t][1]);
    }

    __syncthreads();   // lds_se ready

    float best[4][4], second[4][4];
    int bk[4][4];
    #pragma unroll
    for (int t = 0; t < 4; t++)
        #pragma unroll
        for (int r = 0; r < 4; r++) {
            best[t][r] = __builtin_inff(); second[t][r] = __builtin_inff(); bk[t][r] = 0;
        }

    // 32 code-tiles of 16. B[n=lane&15][k=g*8+j] = e[code][k]: contiguous e-row
    // slice, converted fp32->bf16 hi/lo on the fly (emb is L1-hot, 128 KB).
    for (int tile = 0; tile < 32; tile++) {
        const int code = tile * 16 + m;
        const float* ep = emb + (size_t)code * 64 + g * 8;
        bf16x8 Bh0, Bl0, Bh1, Bl1;
        cvt8(*(const float4*)(ep),      *(const float4*)(ep + 4),  &Bh0, &Bl0);
        cvt8(*(const float4*)(ep + 32), *(const float4*)(ep + 36), &Bh1, &Bl1);
        const float sec = lds_se[code];
        #pragma unroll
        for (int t = 0; t < 4; t++) {
            f32x4 C = {0.f, 0.f, 0.f, 0.f};
            C = __builtin_amdgcn_mfma_f32_16x16x32_bf16(Ah[t][0], Bh0, C, 0, 0, 0);
            C = __builtin_amdgcn_mfma_f32_16x16x32_bf16(Ah[t][1], Bh1, C, 0, 0, 0);
            C = __builtin_amdgcn_mfma_f32_16x16x32_bf16(Al[t][0], Bh0, C, 0, 0, 0);
            C = __builtin_amdgcn_mfma_f32_16x16x32_bf16(Al[t][1], Bh1, C, 0, 0, 0);
            C = __builtin_amdgcn_mfma_f32_16x16x32_bf16(Ah[t][0], Bl0, C, 0, 0, 0);
            C = __builtin_amdgcn_mfma_f32_16x16x32_bf16(Ah[t][1], Bl1, C, 0, 0, 0);
            // (lo*lo dropped: |sum xl*el| <= ~2e-6, well under MARGIN)
            #pragma unroll
            for (int r = 0; r < 4; r++) {
                float s_ = fmaf(-2.f, C[r], sec);   // sx cancels in argmin
                if (s_ < best[t][r]) { second[t][r] = best[t][r]; best[t][r] = s_; bk[t][r] = code; }
                else if (s_ < second[t][r]) second[t][r] = s_;
            }
        }
    }

    // butterfly min over the 16 m-lanes (same g => same row, different code)
    #pragma unroll
    for (int off = 1; off < 16; off <<= 1) {
        #pragma unroll
        for (int t = 0; t < 4; t++)
            #pragma unroll
            for (int r = 0; r < 4; r++) {
                float ob = __shfl_xor(best[t][r], off, 64);
                int   ok = __shfl_xor(bk[t][r], off, 64);
                float os = __shfl_xor(second[t][r], off, 64);
                if (ob < best[t][r]) {
                    second[t][r] = fminf(best[t][r], os);
                    best[t][r] = ob; bk[t][r] = ok;
                } else {
                    second[t][r] = fminf(second[t][r], ob);
                }
            }
    }

    // lane (g,m) publishes row t*16+g*4+r where t=m>>2, r=m&3 (covers all 64)
    {
        const int t = m >> 2, r = m & 3;
        unsigned int f = (second[t][r] - best[t][r] <= MARGIN) ? 0x80000000u : 0u;
        bk_lds[wbase + t * 16 + g * 4 + r] = (unsigned int)bk[t][r] | f;
    }
    __syncthreads();

    // index output (negative = flagged for exact recheck) + histogram
    {
        unsigned int kf = bk_lds[wbase + lane];
        int k0 = (int)(kf & 0xFFFFu);
        out[OFF_IDX + (size_t)(rowbase + lane)] =
            (kf >> 31) ? -(float)(k0 + 1) : (float)k0;
        atomicAdd(&lds_hist[k0], 1u);
    }

    // quantized + loss + one-hot (zeros with embedded 1.0, single coalesced pass)
    float loss = 0.f;
    float2* encb = (float2*)(out + OFF_ENC + (size_t)rowbase * K);
    for (int r2 = 0; r2 < 64; r2++) {
        const unsigned int kb = bk_lds[wbase + r2] & 0xFFFFu;   // uniform broadcast
        float e = emb[kb * 64 + lane];
        float xv = x[(size_t)(rowbase + r2) * 64 + lane];
        out[OFF_Q + (size_t)(rowbase + r2) * 64 + lane] = e;
        float df = e - xv; loss = fmaf(df, df, loss);
        #pragma unroll
        for (int q = 0; q < 4; q++) {
            int col2 = q * 64 + lane;
            float2 v = make_float2(0.f, 0.f);
            if (col2 == (int)(kb >> 1)) { if (kb & 1) v.y = 1.f; else v.x = 1.f; }
            encb[(r2 * 4 + q) * 64 + lane] = v;
        }
    }
    for (int off = 32; off; off >>= 1) loss += __shfl_down(loss, off, 64);
    if (lane == 0) atomicAdd((float*)ws + WS_LOSS, loss);

    __syncthreads();
    atomicAdd(ws + WS_HIST + tid, lds_hist[tid]);
    atomicAdd(ws + WS_HIST + tid + BLOCK, lds_hist[tid + BLOCK]);
}

// ---- cleanup: exact R4-formula argmin on flagged (negative-idx) rows ----
__global__ __launch_bounds__(256) void vq_fix(
    const float* __restrict__ x, const float* __restrict__ emb,
    float* __restrict__ out, unsigned int* __restrict__ ws)
{
    const int lane = threadIdx.x & 63;
    const int wv = blockIdx.x * 4 + (threadIdx.x >> 6);
    const int nw = FIXBLOCKS * 4;

    for (int base = wv * 64; base < N_ROWS; base += nw * 64) {
        float v = out[OFF_IDX + (size_t)base + lane];
        unsigned long long msk = __ballot(v < 0.f);
        while (msk) {
            const int rbit = __ffsll((unsigned long long)msk) - 1;
            msk &= msk - 1;
            const int row = base + rbit;
            const int k0 = (int)(-__shfl(v, rbit, 64)) - 1;   // approx winner

            float4 xr[16];
            const float4* xp = (const float4*)(x + (size_t)row * D);
            #pragma unroll
            for (int j = 0; j < 16; j++) xr[j] = xp[j];
            float4 sa = make_float4(0.f, 0.f, 0.f, 0.f);
            #pragma unroll
            for (int j = 0; j < 16; j++) {
                sa.x = fmaf(xr[j].x, xr[j].x, sa.x); sa.y = fmaf(xr[j].y, xr[j].y, sa.y);
                sa.z = fmaf(xr[j].z, xr[j].z, sa.z); sa.w = fmaf(xr[j].w, xr[j].w, sa.w);
            }
            const float sx = (sa.x + sa.y) + (sa.z + sa.w);

            float dloc[8];
            float bd = __builtin_inff(); int bK = 0;
            #pragma unroll
            for (int c = 0; c < 8; c++) {
                const int k = lane * 8 + c;                 // ascending within lane
                const float4* ep = (const float4*)(emb + (size_t)k * D);
                float se = 0.f;                              // exact R4 se chain
                float4 a0 = make_float4(0.f, 0.f, 0.f, 0.f);
                #pragma unroll
                for (int j = 0; j < 16; j++) {
                    float4 e = ep[j];
                    se = fmaf(e.x, e.x, se); se = fmaf(e.y, e.y, se);
                    se = fmaf(e.z, e.z, se); se = fmaf(e.w, e.w, se);
                    a0.x = fmaf(xr[j].x, e.x, a0.x); a0.y = fmaf(xr[j].y, e.y, a0.y);
                    a0.z = fmaf(xr[j].z, e.z, a0.z); a0.w = fmaf(xr[j].w, e.w, a0.w);
                }
                float dot = (a0.x + a0.y) + (a0.z + a0.w);
                float d = fmaf(-2.f, dot, sx + se);         // exact R4 formula
                dloc[c] = d;
                if (d < bd) { bd = d; bK = k; }
            }
            for (int off = 1; off < 64; off <<= 1) {        // lexicographic (d, k)
                float od = __shfl_xor(bd, off, 64);
                int   ok = __shfl_xor(bK, off, 64);
                if (od < bd || (od == bd && ok < bK)) { bd = od; bK = ok; }
            }

            if (lane == 0) out[OFF_IDX + (size_t)row] = (float)bK;  // always unflag
            if (bK != k0) {
                int c0 = k0 & 7;
                float ds = dloc[0];
                ds = (c0 == 1) ? dloc[1] : ds; ds = (c0 == 2) ? dloc[2] : ds;
                ds = (c0 == 3) ? dloc[3] : ds; ds = (c0 == 4) ? dloc[4] : ds;
                ds = (c0 == 5) ? dloc[5] : ds; ds = (c0 == 6) ? dloc[6] : ds;
                ds = (c0 == 7) ? dloc[7] : ds;
                float d0 = __shfl(ds, k0 >> 3, 64);         // exact d(k0)
                out[OFF_Q + (size_t)row * D + lane] = emb[(size_t)bK * D + lane];
                if (lane == 0) {
                    out[OFF_ENC + (size_t)row * K + k0] = 0.f;
                    out[OFF_ENC + (size_t)row * K + bK] = 1.f;
                    atomicAdd(ws + WS_HIST + k0, 0xFFFFFFFFu);   // -1
                    atomicAdd(ws + WS_HIST + bK, 1u);
                    atomicAdd((float*)ws + WS_LOSS, bd - d0);
                }
            }
        }
    }
}

__global__ __launch_bounds__(K) void vq_finalize(
    const unsigned int* __restrict__ ws, float* __restrict__ out)
{
    __shared__ float red[K / 64];
    const int tid = threadIdx.x;
    float p = (float)ws[WS_HIST + tid] * (1.0f / (float)N_ROWS);
    float s = p * logf(p + 1e-10f);
    for (int off = 32; off; off >>= 1) s += __shfl_down(s, off, 64);
    if ((tid & 63) == 0) red[tid >> 6] = s;
    __syncthreads();
    if (tid == 0) {
        float t = 0.f;
        for (int w = 0; w < K / 64; w++) t += red[w];
        out[OFF_PERP] = expf(-t);
        float mloss = ((const float*)ws)[WS_LOSS] * (1.0f / (float)(N_ROWS * D));
        out[OFF_LOSS] = mloss + 0.25f * mloss;  // q_latent + COMMITMENT_COST * e_latent
    }
}

extern "C" void kernel_launch(void* const* d_in, const int* in_sizes, int n_in,
                              void* d_out, int out_size, void* d_ws, size_t ws_size,
                              hipStream_t stream)
{
    const float* x   = (const float*)d_in[0];   // [16,16384,64] fp32
    const float* emb = (const float*)d_in[1];   // [512,64] fp32
    float* out = (float*)d_out;
    unsigned int* ws = (unsigned int*)d_ws;

    hipMemsetAsync(d_ws, 0, (WS_HIST + K) * 4, stream);   // 2112 B: loss+hist
    vq_main<<<GRID, BLOCK, 0, stream>>>(x, emb, out, ws);
    vq_fix<<<FIXBLOCKS, 256, 0, stream>>>(x, emb, out, ws);
    vq_finalize<<<1, K, 0, stream>>>(ws, out);
}

// Round 7
// 1018.539 us; speedup vs baseline: 1.1269x; 1.1269x over previous
//
#include <hip/hip_runtime.h>
#include <math.h>

typedef __attribute__((ext_vector_type(8))) short bf16x8;   // 8 bf16 in 4 VGPRs
typedef __attribute__((ext_vector_type(4))) float f32x4;

#define N_ROWS (16 * 16384)          // 262144 rows
#define D 64
#define K 512
#define BLOCK 256                    // 4 waves; each wave owns 64 rows
#define ROWS_PER_BLOCK 256
#define GRID (N_ROWS / ROWS_PER_BLOCK)   // 1024 blocks
#define MARGIN 1e-4f                 // ~10x the approx-vs-exact score error bound
#define FIXBLOCKS 256                // 1024 waves for the cleanup scan

// d_out layout (float element offsets), outputs concatenated in return order:
// vq_loss[1], quantized_st[N*D], perplexity[1], encodings[N*K], indices[N]
#define OFF_LOSS 0ULL
#define OFF_Q    1ULL
#define OFF_PERP (1ULL + (unsigned long long)N_ROWS * D)        // 16777217
#define OFF_ENC  (OFF_PERP + 1ULL)                               // 16777218
#define OFF_IDX  (OFF_ENC + (unsigned long long)N_ROWS * K)      // 150994946

// ws layout (u32 element offsets) — R5's bug was EHI sized 8192 u32 (half!).
// ehi/elo each need 512*64 ushorts = 16384 u32. Total ws use = 135232 B.
#define WS_LOSS 0       // f32
#define WS_HIST 16      // u32[512]   [16, 528)
#define WS_SE   528     // f32[512]   [528, 1040)
#define WS_EHI  1040    // ushort[32768] = u32[16384]  [1040, 17424)
#define WS_ELO  17424   // ushort[32768] = u32[16384]  [17424, 33808)

__device__ __forceinline__ unsigned short f2bf(float f) {     // RNE fp32->bf16
    unsigned int u = __float_as_uint(f);
    return (unsigned short)((u + 0x7FFFu + ((u >> 16) & 1u)) >> 16);
}
__device__ __forceinline__ float bf2f(unsigned short h) {
    return __uint_as_float(((unsigned int)h) << 16);
}
__device__ __forceinline__ void cvt8(float4 a, float4 b, bf16x8* hi, bf16x8* lo) {
    float v[8] = {a.x, a.y, a.z, a.w, b.x, b.y, b.z, b.w};
    #pragma unroll
    for (int j = 0; j < 8; j++) {
        unsigned short h = f2bf(v[j]);
        (*hi)[j] = (short)h;
        (*lo)[j] = (short)f2bf(v[j] - bf2f(h));
    }
}

// ---- pre-pass: codebook -> bf16 hi/lo B-fragments + ||e||^2 ----
__global__ __launch_bounds__(256) void vq_pre(const float* __restrict__ emb,
                                              unsigned int* __restrict__ ws)
{
    const int t = blockIdx.x * 256 + threadIdx.x;   // code id 0..511
    unsigned short* ehi = (unsigned short*)(ws + WS_EHI);
    unsigned short* elo = (unsigned short*)(ws + WS_ELO);
    uint2* dh = (uint2*)(ehi + t * 64);
    uint2* dl = (uint2*)(elo + t * 64);
    const float4* e4 = (const float4*)(emb + (size_t)t * D);
    float4 sa = make_float4(0.f, 0.f, 0.f, 0.f);
    #pragma unroll
    for (int i = 0; i < 16; i++) {
        float4 e = e4[i];
        sa.x = fmaf(e.x, e.x, sa.x); sa.y = fmaf(e.y, e.y, sa.y);
        sa.z = fmaf(e.z, e.z, sa.z); sa.w = fmaf(e.w, e.w, sa.w);
        unsigned short h0 = f2bf(e.x), h1 = f2bf(e.y), h2 = f2bf(e.z), h3 = f2bf(e.w);
        unsigned short l0 = f2bf(e.x - bf2f(h0)), l1 = f2bf(e.y - bf2f(h1));
        unsigned short l2 = f2bf(e.z - bf2f(h2)), l3 = f2bf(e.w - bf2f(h3));
        dh[i] = make_uint2((unsigned)h0 | ((unsigned)h1 << 16),
                           (unsigned)h2 | ((unsigned)h3 << 16));
        dl[i] = make_uint2((unsigned)l0 | ((unsigned)l1 << 16),
                           (unsigned)l2 | ((unsigned)l3 << 16));
    }
    ((float*)ws)[WS_SE + t] = (sa.x + sa.y) + (sa.z + sa.w);
}

// ---- main: MFMA split-bf16 distances + argmin + all outputs ----
// launch_bounds WITHOUT a 2nd arg + waves_per_eu(2,2): pins the allocator's
// occupancy target (R4-proven). A 2nd launch_bounds arg makes LLVM target the
// MAX of the waves/EU range -> 84-VGPR squeeze + ~1.1 GB scratch spill (R6).
__global__ __launch_bounds__(BLOCK)
__attribute__((amdgpu_waves_per_eu(2, 2)))
void vq_main(
    const float* __restrict__ x, const float* __restrict__ emb,
    float* __restrict__ out, unsigned int* __restrict__ ws)
{
    __shared__ float lds_se[K];                // 2 KB ||e||^2
    __shared__ unsigned int bk_lds[BLOCK];     // per-row winner (+flag bit31)
    __shared__ unsigned int lds_hist[K];

    const int tid = threadIdx.x, lane = tid & 63, wave = tid >> 6;
    const int m = lane & 15, g = lane >> 4;    // MFMA lane decomposition
    const int rowbase = blockIdx.x * ROWS_PER_BLOCK + wave * 64;
    const int wbase = wave * 64;

    lds_hist[tid] = 0; lds_hist[tid + BLOCK] = 0;
    lds_se[tid] = ((const float*)ws)[WS_SE + tid];
    lds_se[tid + BLOCK] = ((const float*)ws)[WS_SE + tid + BLOCK];

    // A-fragments: 64 rows as bf16 hi/lo. A[m=lane&15][k=g*8+j], per K=32 window
    bf16x8 Ah[4][2], Al[4][2];
    #pragma unroll
    for (int t = 0; t < 4; t++) {
        const float* xb = x + (size_t)(rowbase + t * 16 + m) * D + g * 8;
        cvt8(*(const float4*)(xb),      *(const float4*)(xb + 4),  &Ah[t][0], &Al[t][0]);
        cvt8(*(const float4*)(xb + 32), *(const float4*)(xb + 36), &Ah[t][1], &Al[t][1]);
    }

    __syncthreads();   // lds_se ready

    const unsigned short* ehi = (const unsigned short*)(ws + WS_EHI);
    const unsigned short* elo = (const unsigned short*)(ws + WS_ELO);

    float best[4][4], second[4][4];
    int bk[4][4];
    #pragma unroll
    for (int t = 0; t < 4; t++)
        #pragma unroll
        for (int r = 0; r < 4; r++) {
            best[t][r] = __builtin_inff(); second[t][r] = __builtin_inff(); bk[t][r] = 0;
        }

    // 32 code-tiles of 16. B[n=lane&15][k=g*8+j] = e[code][k]: 16B loads from
    // the precomputed L2-hot tables (no per-tile conversion VALU).
    for (int tile = 0; tile < 32; tile++) {
        const int code = tile * 16 + m;
        const size_t boff = (size_t)code * 64 + g * 8;
        bf16x8 Bh0 = *(const bf16x8*)(ehi + boff);
        bf16x8 Bh1 = *(const bf16x8*)(ehi + boff + 32);
        bf16x8 Bl0 = *(const bf16x8*)(elo + boff);
        bf16x8 Bl1 = *(const bf16x8*)(elo + boff + 32);
        const float sec = lds_se[code];
        #pragma unroll
        for (int t = 0; t < 4; t++) {
            f32x4 C = {0.f, 0.f, 0.f, 0.f};
            C = __builtin_amdgcn_mfma_f32_16x16x32_bf16(Ah[t][0], Bh0, C, 0, 0, 0);
            C = __builtin_amdgcn_mfma_f32_16x16x32_bf16(Ah[t][1], Bh1, C, 0, 0, 0);
            C = __builtin_amdgcn_mfma_f32_16x16x32_bf16(Al[t][0], Bh0, C, 0, 0, 0);
            C = __builtin_amdgcn_mfma_f32_16x16x32_bf16(Al[t][1], Bh1, C, 0, 0, 0);
            C = __builtin_amdgcn_mfma_f32_16x16x32_bf16(Ah[t][0], Bl0, C, 0, 0, 0);
            C = __builtin_amdgcn_mfma_f32_16x16x32_bf16(Ah[t][1], Bl1, C, 0, 0, 0);
            // (lo*lo dropped: |sum xl*el| <= ~2e-6, well under MARGIN)
            #pragma unroll
            for (int r = 0; r < 4; r++) {
                float s_ = fmaf(-2.f, C[r], sec);   // sx cancels in argmin
                if (s_ < best[t][r]) { second[t][r] = best[t][r]; best[t][r] = s_; bk[t][r] = code; }
                else if (s_ < second[t][r]) second[t][r] = s_;
            }
        }
    }

    // butterfly min over the 16 m-lanes (same g => same row, different code)
    #pragma unroll
    for (int off = 1; off < 16; off <<= 1) {
        #pragma unroll
        for (int t = 0; t < 4; t++)
            #pragma unroll
            for (int r = 0; r < 4; r++) {
                float ob = __shfl_xor(best[t][r], off, 64);
                int   ok = __shfl_xor(bk[t][r], off, 64);
                float os = __shfl_xor(second[t][r], off, 64);
                if (ob < best[t][r]) {
                    second[t][r] = fminf(best[t][r], os);
                    best[t][r] = ob; bk[t][r] = ok;
                } else {
                    second[t][r] = fminf(second[t][r], ob);
                }
            }
    }

    // lane (g,m) publishes row t*16+g*4+r where t=m>>2, r=m&3 (covers all 64)
    {
        const int t = m >> 2, r = m & 3;
        unsigned int f = (second[t][r] - best[t][r] <= MARGIN) ? 0x80000000u : 0u;
        bk_lds[wbase + t * 16 + g * 4 + r] = (unsigned int)bk[t][r] | f;
    }
    __syncthreads();

    // index output (negative = flagged for exact recheck) + histogram
    {
        unsigned int kf = bk_lds[wbase + lane];
        int k0 = (int)(kf & 0xFFFFu);
        out[OFF_IDX + (size_t)(rowbase + lane)] =
            (kf >> 31) ? -(float)(k0 + 1) : (float)k0;
        atomicAdd(&lds_hist[k0], 1u);
    }

    // quantized + loss + one-hot (zeros with embedded 1.0, single coalesced pass)
    float loss = 0.f;
    float2* encb = (float2*)(out + OFF_ENC + (size_t)rowbase * K);
    for (int r2 = 0; r2 < 64; r2++) {
        const unsigned int kb = bk_lds[wbase + r2] & 0xFFFFu;   // uniform broadcast
        float e = emb[kb * 64 + lane];
        float xv = x[(size_t)(rowbase + r2) * 64 + lane];
        out[OFF_Q + (size_t)(rowbase + r2) * 64 + lane] = e;
        float df = e - xv; loss = fmaf(df, df, loss);
        #pragma unroll
        for (int q = 0; q < 4; q++) {
            int col2 = q * 64 + lane;
            float2 v = make_float2(0.f, 0.f);
            if (col2 == (int)(kb >> 1)) { if (kb & 1) v.y = 1.f; else v.x = 1.f; }
            encb[(r2 * 4 + q) * 64 + lane] = v;
        }
    }
    for (int off = 32; off; off >>= 1) loss += __shfl_down(loss, off, 64);
    if (lane == 0) atomicAdd((float*)ws + WS_LOSS, loss);

    __syncthreads();
    atomicAdd(ws + WS_HIST + tid, lds_hist[tid]);
    atomicAdd(ws + WS_HIST + tid + BLOCK, lds_hist[tid + BLOCK]);
}

// ---- cleanup: exact R4-formula argmin on flagged (negative-idx) rows ----
__global__ __launch_bounds__(256) void vq_fix(
    const float* __restrict__ x, const float* __restrict__ emb,
    float* __restrict__ out, unsigned int* __restrict__ ws)
{
    const int lane = threadIdx.x & 63;
    const int wv = blockIdx.x * 4 + (threadIdx.x >> 6);
    const int nw = FIXBLOCKS * 4;

    for (int base = wv * 64; base < N_ROWS; base += nw * 64) {
        float v = out[OFF_IDX + (size_t)base + lane];
        unsigned long long msk = __ballot(v < 0.f);
        while (msk) {
            const int rbit = __ffsll((unsigned long long)msk) - 1;
            msk &= msk - 1;
            const int row = base + rbit;
            const int k0 = (int)(-__shfl(v, rbit, 64)) - 1;   // approx winner

            float4 xr[16];
            const float4* xp = (const float4*)(x + (size_t)row * D);
            #pragma unroll
            for (int j = 0; j < 16; j++) xr[j] = xp[j];
            float4 sa = make_float4(0.f, 0.f, 0.f, 0.f);
            #pragma unroll
            for (int j = 0; j < 16; j++) {
                sa.x = fmaf(xr[j].x, xr[j].x, sa.x); sa.y = fmaf(xr[j].y, xr[j].y, sa.y);
                sa.z = fmaf(xr[j].z, xr[j].z, sa.z); sa.w = fmaf(xr[j].w, xr[j].w, sa.w);
            }
            const float sx = (sa.x + sa.y) + (sa.z + sa.w);

            float dloc[8];
            float bd = __builtin_inff(); int bK = 0;
            #pragma unroll
            for (int c = 0; c < 8; c++) {
                const int k = lane * 8 + c;                 // ascending within lane
                const float4* ep = (const float4*)(emb + (size_t)k * D);
                float se = 0.f;                              // exact R4 se chain
                float4 a0 = make_float4(0.f, 0.f, 0.f, 0.f);
                #pragma unroll
                for (int j = 0; j < 16; j++) {
                    float4 e = ep[j];
                    se = fmaf(e.x, e.x, se); se = fmaf(e.y, e.y, se);
                    se = fmaf(e.z, e.z, se); se = fmaf(e.w, e.w, se);
                    a0.x = fmaf(xr[j].x, e.x, a0.x); a0.y = fmaf(xr[j].y, e.y, a0.y);
                    a0.z = fmaf(xr[j].z, e.z, a0.z); a0.w = fmaf(xr[j].w, e.w, a0.w);
                }
                float dot = (a0.x + a0.y) + (a0.z + a0.w);
                float d = fmaf(-2.f, dot, sx + se);         // exact R4 formula
                dloc[c] = d;
                if (d < bd) { bd = d; bK = k; }
            }
            for (int off = 1; off < 64; off <<= 1) {        // lexicographic (d, k)
                float od = __shfl_xor(bd, off, 64);
                int   ok = __shfl_xor(bK, off, 64);
                if (od < bd || (od == bd && ok < bK)) { bd = od; bK = ok; }
            }

            if (lane == 0) out[OFF_IDX + (size_t)row] = (float)bK;  // always unflag
            if (bK != k0) {
                int c0 = k0 & 7;
                float ds = dloc[0];
                ds = (c0 == 1) ? dloc[1] : ds; ds = (c0 == 2) ? dloc[2] : ds;
                ds = (c0 == 3) ? dloc[3] : ds; ds = (c0 == 4) ? dloc[4] : ds;
                ds = (c0 == 5) ? dloc[5] : ds; ds = (c0 == 6) ? dloc[6] : ds;
                ds = (c0 == 7) ? dloc[7] : ds;
                float d0 = __shfl(ds, k0 >> 3, 64);         // exact d(k0)
                out[OFF_Q + (size_t)row * D + lane] = emb[(size_t)bK * D + lane];
                if (lane == 0) {
                    out[OFF_ENC + (size_t)row * K + k0] = 0.f;
                    out[OFF_ENC + (size_t)row * K + bK] = 1.f;
                    atomicAdd(ws + WS_HIST + k0, 0xFFFFFFFFu);   // -1
                    atomicAdd(ws + WS_HIST + bK, 1u);
                    atomicAdd((float*)ws + WS_LOSS, bd - d0);
                }
            }
        }
    }
}

__global__ __launch_bounds__(K) void vq_finalize(
    const unsigned int* __restrict__ ws, float* __restrict__ out)
{
    __shared__ float red[K / 64];
    const int tid = threadIdx.x;
    float p = (float)ws[WS_HIST + tid] * (1.0f / (float)N_ROWS);
    float s = p * logf(p + 1e-10f);
    for (int off = 32; off; off >>= 1) s += __shfl_down(s, off, 64);
    if ((tid & 63) == 0) red[tid >> 6] = s;
    __syncthreads();
    if (tid == 0) {
        float t = 0.f;
        for (int w = 0; w < K / 64; w++) t += red[w];
        out[OFF_PERP] = expf(-t);
        float mloss = ((const float*)ws)[WS_LOSS] * (1.0f / (float)(N_ROWS * D));
        out[OFF_LOSS] = mloss + 0.25f * mloss;  // q_latent + COMMITMENT_COST * e_latent
    }
}

extern "C" void kernel_launch(void* const* d_in, const int* in_sizes, int n_in,
                              void* d_out, int out_size, void* d_ws, size_t ws_size,
                              hipStream_t stream)
{
    const float* x   = (const float*)d_in[0];   // [16,16384,64] fp32
    const float* emb = (const float*)d_in[1];   // [512,64] fp32
    float* out = (float*)d_out;
    unsigned int* ws = (unsigned int*)d_ws;

    hipMemsetAsync(d_ws, 0, (WS_HIST + K) * 4, stream);   // loss+hist only
    vq_pre<<<2, 256, 0, stream>>>(emb, ws);
    vq_main<<<GRID, BLOCK, 0, stream>>>(x, emb, out, ws);
    vq_fix<<<FIXBLOCKS, 256, 0, stream>>>(x, emb, out, ws);
    vq_finalize<<<1, K, 0, stream>>>(ws, out);
}